// Round 1
// baseline (290.834 us; speedup 1.0000x reference)
//
#include <hip/hip_runtime.h>
#include <math.h>

#define Bn    4
#define HIDc  64          // hidden / input channels each = 64
#define INCc  128         // concat channels
#define OUTCc 256         // 4*HID gates
#define Dd    256         // meta dim
#define NT    9           // K*K taps
#define KKk   (INCc*NT)   // 1152 contraction length
#define HWn   4096        // 64*64

// ---- workspace layout (floats) ----
// wm1 : [B][INC][D]      = 131072
// Wk  : [B][KK][OUTC]    = 1179648   (k = c*9+n, o contiguous)
// bm  : [B][OUTC]        = 1024
#define WM1_OFF 0
#define WK_OFF  (Bn*INCc*Dd)
#define BM_OFF  (WK_OFF + Bn*KKk*OUTCc)

__device__ __forceinline__ float sigf(float x) { return 1.f / (1.f + __expf(-x)); }
__device__ __forceinline__ float tanhfast(float x) {
    float a = fabsf(x);
    float e = __expf(2.f * a);          // inf-safe: e=inf -> t=1
    float t = 1.f - 2.f / (e + 1.f);
    return copysignf(t, x);
}

// ---------------------------------------------------------------------------
// Kernel 1: wm1[b][r] = meta[b,:] . w1_w[r,:] + w1_b[r]   (r = c*256+d)
//           block 128: bm[b][o] = meta[b,:] . bl_w[o,:] + bl_b[o]
// ---------------------------------------------------------------------------
__global__ void __launch_bounds__(256)
k_hyper(const float* __restrict__ meta, const float* __restrict__ w1w,
        const float* __restrict__ w1b, const float* __restrict__ blw,
        const float* __restrict__ blb, float* __restrict__ ws)
{
    __shared__ __align__(16) float sm[Bn * Dd];
    int t = threadIdx.x;
    for (int i = t; i < Bn * Dd; i += 256) sm[i] = meta[i];
    __syncthreads();

    if (blockIdx.x == 128) {                    // bias path: bm
        int o = t;
        float a0 = blb[o], a1 = a0, a2 = a0, a3 = a0;
        const float* wr = blw + (size_t)o * Dd;
        for (int d = 0; d < Dd; d += 4) {
            float4 wv = *(const float4*)(wr + d);
            a0 += wv.x*sm[0*Dd+d] + wv.y*sm[0*Dd+d+1] + wv.z*sm[0*Dd+d+2] + wv.w*sm[0*Dd+d+3];
            a1 += wv.x*sm[1*Dd+d] + wv.y*sm[1*Dd+d+1] + wv.z*sm[1*Dd+d+2] + wv.w*sm[1*Dd+d+3];
            a2 += wv.x*sm[2*Dd+d] + wv.y*sm[2*Dd+d+1] + wv.z*sm[2*Dd+d+2] + wv.w*sm[2*Dd+d+3];
            a3 += wv.x*sm[3*Dd+d] + wv.y*sm[3*Dd+d+1] + wv.z*sm[3*Dd+d+2] + wv.w*sm[3*Dd+d+3];
        }
        ws[BM_OFF + 0*OUTCc + o] = a0;
        ws[BM_OFF + 1*OUTCc + o] = a1;
        ws[BM_OFF + 2*OUTCc + o] = a2;
        ws[BM_OFF + 3*OUTCc + o] = a3;
    } else {                                    // wm1 rows
        int r = blockIdx.x * 256 + t;
        const float* wr = w1w + (size_t)r * Dd;
        float bias = w1b[r];
        float a0 = bias, a1 = bias, a2 = bias, a3 = bias;
        for (int d = 0; d < Dd; d += 4) {
            float4 wv = *(const float4*)(wr + d);
            a0 += wv.x*sm[0*Dd+d] + wv.y*sm[0*Dd+d+1] + wv.z*sm[0*Dd+d+2] + wv.w*sm[0*Dd+d+3];
            a1 += wv.x*sm[1*Dd+d] + wv.y*sm[1*Dd+d+1] + wv.z*sm[1*Dd+d+2] + wv.w*sm[1*Dd+d+3];
            a2 += wv.x*sm[2*Dd+d] + wv.y*sm[2*Dd+d+1] + wv.z*sm[2*Dd+d+2] + wv.w*sm[2*Dd+d+3];
            a3 += wv.x*sm[3*Dd+d] + wv.y*sm[3*Dd+d+1] + wv.z*sm[3*Dd+d+2] + wv.w*sm[3*Dd+d+3];
        }
        ws[WM1_OFF + 0*INCc*Dd + r] = a0;
        ws[WM1_OFF + 1*INCc*Dd + r] = a1;
        ws[WM1_OFF + 2*INCc*Dd + r] = a2;
        ws[WM1_OFF + 3*INCc*Dd + r] = a3;
    }
}

// ---------------------------------------------------------------------------
// Kernel 2: per-sample GEMM  C[c,j] = wm1[b][c,:] . w2_w[j,:]  (+ w2_b[j])
//           scatter-store into Wk[b][c*9 + j%9][j/9]
// 64x64 tiles, 256 thr, 4x4 micro, K-chunk 32, transposed LDS tiles (stride 68)
// ---------------------------------------------------------------------------
__global__ void __launch_bounds__(256)
k_w2(const float* __restrict__ w2w, const float* __restrict__ w2b,
     float* __restrict__ ws)
{
    int bid = blockIdx.x;
    int b   = bid / 72;
    int r   = bid % 72;
    int mt  = r / 36, nt = r % 36;
    int c0  = mt * 64, j0 = nt * 64;

    __shared__ __align__(16) float At[32][68];
    __shared__ __align__(16) float Bt[32][68];

    const float* A = ws + WM1_OFF + (size_t)b * INCc * Dd;  // [128][256]
    int t  = threadIdx.x;
    int ty = t >> 4, tx = t & 15;
    int lr = t >> 2;        // 0..63 tile row
    int lf = t & 3;         // float4 slot

    float acc[4][4];
#pragma unroll
    for (int i = 0; i < 4; i++)
#pragma unroll
        for (int q = 0; q < 4; q++) acc[i][q] = 0.f;

    for (int dk = 0; dk < Dd; dk += 32) {
        __syncthreads();
#pragma unroll
        for (int s = 0; s < 2; s++) {
            int f4 = lf + s * 4;      // 0..7
            float4 av = *(const float4*)(A + (size_t)(c0 + lr) * Dd + dk + f4 * 4);
            At[f4*4+0][lr] = av.x; At[f4*4+1][lr] = av.y;
            At[f4*4+2][lr] = av.z; At[f4*4+3][lr] = av.w;
            float4 bv = *(const float4*)(w2w + (size_t)(j0 + lr) * Dd + dk + f4 * 4);
            Bt[f4*4+0][lr] = bv.x; Bt[f4*4+1][lr] = bv.y;
            Bt[f4*4+2][lr] = bv.z; Bt[f4*4+3][lr] = bv.w;
        }
        __syncthreads();
#pragma unroll 4
        for (int d = 0; d < 32; d++) {
            float4 a4 = *(const float4*)&At[d][ty * 4];
            float4 b4 = *(const float4*)&Bt[d][tx * 4];
            acc[0][0] += a4.x*b4.x; acc[0][1] += a4.x*b4.y; acc[0][2] += a4.x*b4.z; acc[0][3] += a4.x*b4.w;
            acc[1][0] += a4.y*b4.x; acc[1][1] += a4.y*b4.y; acc[1][2] += a4.y*b4.z; acc[1][3] += a4.y*b4.w;
            acc[2][0] += a4.z*b4.x; acc[2][1] += a4.z*b4.y; acc[2][2] += a4.z*b4.z; acc[2][3] += a4.z*b4.w;
            acc[3][0] += a4.w*b4.x; acc[3][1] += a4.w*b4.y; acc[3][2] += a4.w*b4.z; acc[3][3] += a4.w*b4.w;
        }
    }

#pragma unroll
    for (int i = 0; i < 4; i++) {
        int c = c0 + ty * 4 + i;
#pragma unroll
        for (int q = 0; q < 4; q++) {
            int j = j0 + tx * 4 + q;
            int o = j / 9, n = j - o * 9;
            ws[WK_OFF + ((size_t)b * KKk + c * NT + n) * OUTCc + o] = acc[i][q] + w2b[j];
        }
    }
}

// ---------------------------------------------------------------------------
// Kernel 3: fused offset-conv + deformable bilinear sampling + dynamic conv
//           (per-sample GEMM over k=c*9+n) + LSTM gate epilogue.
// Grid 512: XCD-swizzled (b from bid&7 so each sample's W slab lives in 2 XCD L2s)
// Block 256: 32-pixel half-row tile, micro-tile 4px x (2ch x 4gates).
// ---------------------------------------------------------------------------
__global__ void __launch_bounds__(256)
k_main(const float* __restrict__ xin, const float* __restrict__ hcur,
       const float* __restrict__ ccur, const float* __restrict__ moff,
       const float* __restrict__ pw, const float* __restrict__ pb,
       const float* __restrict__ ws, float* __restrict__ out)
{
    int bid  = blockIdx.x;
    int xcd  = bid & 7;
    int b    = xcd >> 1;                      // 2 XCD slots per sample
    int tile = ((bid >> 3) << 1) + (xcd & 1); // 0..127
    int h    = tile >> 1;
    int w0   = (tile & 1) * 32;

    __shared__ __align__(16) int   sIdx[NT][4][32];
    __shared__ __align__(16) float sWgt[NT][4][32];
    __shared__ __align__(16) float Wsh[4 * NT * OUTCc];   // 9216 floats
    __shared__ __align__(16) float Xs[4 * NT][32];
    __shared__ float bmS[OUTCc];

    int t = threadIdx.x;
    bmS[t] = ws[BM_OFF + (size_t)b * OUTCc + t];

    // ---- phase 0: offsets (p_conv inline) + bilinear tables per (px, n) ----
    {
        int px   = t & 31;
        int nh   = t >> 5;                 // 0..7 ; nh==0 also does n=8
        int wpos = w0 + px;
        for (int n = nh; n < NT; n += 8) {
            float ox = pb[n], oy = pb[NT + n];
#pragma unroll
            for (int ii = 0; ii < 3; ii++) {
#pragma unroll
                for (int jj = 0; jj < 3; jj++) {
                    int rr = h - 1 + ii, cc = wpos - 1 + jj;
                    float m = (rr >= 0 && rr < 64 && cc >= 0 && cc < 64)
                              ? moff[(size_t)b * HWn + rr * 64 + cc] : 0.f;
                    ox = fmaf(pw[(size_t)n * 9 + ii * 3 + jj], m, ox);
                    oy = fmaf(pw[(size_t)(NT + n) * 9 + ii * 3 + jj], m, oy);
                }
            }
            float pr = (float)(h + (n / 3)) + ox;        // (h+1)+(n/3-1)
            float pc = (float)(wpos + (n % 3)) + oy;     // (w+1)+(n%3-1)
            float fr = floorf(pr), fc = floorf(pc);
            float ltr = fminf(fmaxf(fr, 0.f), 65.f);
            float ltc = fminf(fmaxf(fc, 0.f), 65.f);
            float rbr = fminf(fmaxf(fr + 1.f, 0.f), 65.f);
            float rbc = fminf(fmaxf(fc + 1.f, 0.f), 65.f);
            float cpr = fminf(fmaxf(pr, 0.f), 65.f);
            float cpc = fminf(fmaxf(pc, 0.f), 65.f);
            float ar = 1.f + ltr - cpr, br = 1.f - rbr + cpr;
            float ac = 1.f + ltc - cpc, bc = 1.f - rbc + cpc;
            int ir0 = (int)ltr, ic0 = (int)ltc, ir1 = (int)rbr, ic1 = (int)rbc;
            int   rr4[4] = {ir0, ir1, ir0, ir1};
            int   cc4[4] = {ic0, ic1, ic1, ic0};
            float gg4[4] = {ar * ac, br * bc, ar * bc, br * ac};
#pragma unroll
            for (int jj = 0; jj < 4; jj++) {
                bool inb = (rr4[jj] >= 1) && (rr4[jj] <= 64) &&
                           (cc4[jj] >= 1) && (cc4[jj] <= 64);
                sIdx[n][jj][px] = inb ? ((rr4[jj] - 1) * 64 + (cc4[jj] - 1)) : 0;
                sWgt[n][jj][px] = inb ? gg4[jj] : 0.f;
            }
        }
    }
    __syncthreads();

    // ---- register-cache this thread's sampling tables (fixed px across chunks)
    int px   = t & 31;
    int csel = (t >> 5) & 3;
    int half = t >> 7;
    int n0   = half ? 5 : 0;
    int ncnt = half ? 4 : 5;
    int   idxR[5][4];
    float wgtR[5][4];
#pragma unroll
    for (int u = 0; u < 5; u++) {
        if (u < ncnt) {
            int n = n0 + u;
#pragma unroll
            for (int jj = 0; jj < 4; jj++) {
                idxR[u][jj] = sIdx[n][jj][px];
                wgtR[u][jj] = sWgt[n][jj][px];
            }
        }
    }

    int og = t & 31;   // output pair group: o = og*2+q + j*64
    int pg = t >> 5;   // 0..7 : px = pg*4 + pp
    float acc[4][8];
#pragma unroll
    for (int i = 0; i < 4; i++)
#pragma unroll
        for (int q = 0; q < 8; q++) acc[i][q] = 0.f;

    const float* WkB = ws + WK_OFF + (size_t)b * KKk * OUTCc;

    for (int c0 = 0; c0 < INCc; c0 += 4) {
        // W-stage: 9216 contiguous floats -> LDS
        const float* src = WkB + (size_t)c0 * NT * OUTCc;
#pragma unroll
        for (int it = 0; it < 9; it++) {
            *(float4*)&Wsh[it * 1024 + t * 4] = *(const float4*)(src + it * 1024 + t * 4);
        }
        // X-stage: sample 4 channels x 32 px x 9 taps
        {
            int c = c0 + csel;
            const float* plane = (c < HIDc)
                ? (xin  + (size_t)(b * HIDc + c) * HWn)
                : (hcur + (size_t)(b * HIDc + (c - HIDc)) * HWn);
#pragma unroll
            for (int u = 0; u < 5; u++) {
                if (u < ncnt) {
                    int n = n0 + u;
                    float v = wgtR[u][0] * plane[idxR[u][0]]
                            + wgtR[u][1] * plane[idxR[u][1]]
                            + wgtR[u][2] * plane[idxR[u][2]]
                            + wgtR[u][3] * plane[idxR[u][3]];
                    Xs[csel * NT + n][px] = v;
                }
            }
        }
        __syncthreads();
        // main FMA loop over 36 local k
        for (int kk = 0; kk < 4 * NT; kk++) {
            float4 x4 = *(const float4*)&Xs[kk][pg * 4];
            const float* wrow = &Wsh[kk * OUTCc + og * 2];
#pragma unroll
            for (int j = 0; j < 4; j++) {
                float2 w2 = *(const float2*)(wrow + j * 64);
                acc[0][2*j]   += x4.x * w2.x;  acc[0][2*j+1] += x4.x * w2.y;
                acc[1][2*j]   += x4.y * w2.x;  acc[1][2*j+1] += x4.y * w2.y;
                acc[2][2*j]   += x4.z * w2.x;  acc[2][2*j+1] += x4.z * w2.y;
                acc[3][2*j]   += x4.w * w2.x;  acc[3][2*j+1] += x4.w * w2.y;
            }
        }
        __syncthreads();
    }

    // ---- epilogue: gates + LSTM state update (j: 0=i, 1=f, 2=o, 3=g) ----
#pragma unroll
    for (int pp = 0; pp < 4; pp++) {
        int wpos = w0 + pg * 4 + pp;
#pragma unroll
        for (int q = 0; q < 2; q++) {
            int ch = og * 2 + q;
            float ci = acc[pp][0 + q] + bmS[ch];
            float cf = acc[pp][2 + q] + bmS[64 + ch];
            float co = acc[pp][4 + q] + bmS[128 + ch];
            float cg = acc[pp][6 + q] + bmS[192 + ch];
            float ig  = sigf(ci);
            float fg  = sigf(cf);
            float og_ = sigf(co);
            float gg  = tanhfast(cg);
            size_t idx = ((size_t)(b * HIDc + ch) * 64 + h) * 64 + wpos;
            float cprev = ccur[idx];
            float cn = fg * cprev + ig * gg;
            float hn = og_ * tanhfast(cn);
            out[idx] = hn;                                   // h_next
            out[(size_t)Bn * HIDc * HWn + idx] = cn;         // c_next
        }
    }
}

// ---------------------------------------------------------------------------
extern "C" void kernel_launch(void* const* d_in, const int* in_sizes, int n_in,
                              void* d_out, int out_size, void* d_ws, size_t ws_size,
                              hipStream_t stream)
{
    const float* xin  = (const float*)d_in[0];
    const float* hcur = (const float*)d_in[1];
    const float* ccur = (const float*)d_in[2];
    const float* meta = (const float*)d_in[3];
    const float* moff = (const float*)d_in[4];
    const float* w1w  = (const float*)d_in[5];
    const float* w1b  = (const float*)d_in[6];
    const float* w2w  = (const float*)d_in[7];
    const float* w2b  = (const float*)d_in[8];
    const float* blw  = (const float*)d_in[9];
    const float* blb  = (const float*)d_in[10];
    const float* pw   = (const float*)d_in[11];
    const float* pb   = (const float*)d_in[12];
    float* out = (float*)d_out;
    float* ws  = (float*)d_ws;

    hipLaunchKernelGGL(k_hyper, dim3(129), dim3(256), 0, stream,
                       meta, w1w, w1b, blw, blb, ws);
    hipLaunchKernelGGL(k_w2, dim3(288), dim3(256), 0, stream, w2w, w2b, ws);
    hipLaunchKernelGGL(k_main, dim3(512), dim3(256), 0, stream,
                       xin, hcur, ccur, moff, pw, pb, ws, out);
}

// Round 2
// 215.953 us; speedup vs baseline: 1.3468x; 1.3468x over previous
//
#include <hip/hip_runtime.h>
#include <math.h>

#define Bn    4
#define HIDc  64          // hidden / input channels each = 64
#define INCc  128         // concat channels
#define OUTCc 256         // 4*HID gates
#define Dd    256         // meta dim
#define NT    9           // K*K taps
#define HWn   4096        // 64*64
#define NCHUNK 36         // K=1152 in 32-chunks, k = n*128 + c

typedef unsigned short u16;
typedef __attribute__((ext_vector_type(8))) short bs8;   // 8 bf16 (4 VGPRs)
typedef __attribute__((ext_vector_type(4))) float f4;    // MFMA C/D frag

// ---- workspace layout ----
// floats: wm1 [B][INC][D] = 131072 ; bm [B][OUTC] = 1024
// then bf16 planes: Whi / Wlo, each [B][36 kc][256 r][32 kk] u16 (r = ch*4+gate)
#define WM1_OFF 0
#define BM_OFF  (Bn*INCc*Dd)
#define WSPLIT_BYTE ((size_t)(BM_OFF + Bn*OUTCc) * 4)
#define WPLANE  ((size_t)Bn*NCHUNK*256*32)

__device__ __forceinline__ float sigf(float x) { return 1.f / (1.f + __expf(-x)); }
__device__ __forceinline__ float tanhfast(float x) {
    float a = fabsf(x);
    float e = __expf(2.f * a);
    float t = 1.f - 2.f / (e + 1.f);
    return copysignf(t, x);
}
// exact truncating bf16 split: v ~= hi + lo with residual ~2^-16 relative
__device__ __forceinline__ void splitbf(float v, unsigned& h, unsigned& l) {
    unsigned u = __float_as_uint(v);
    h = u >> 16;
    float r = v - __uint_as_float(u & 0xffff0000u);   // exact
    l = __float_as_uint(r) >> 16;
}

// ---------------------------------------------------------------------------
// Kernel 1: wm1[b][r] = meta[b,:] . w1_w[r,:] + w1_b[r]
// 256 blocks x 128 rows, 2 threads/row (d split) + shfl combine; block 256: bm
// ---------------------------------------------------------------------------
__global__ void __launch_bounds__(256)
k_hyper(const float* __restrict__ meta, const float* __restrict__ w1w,
        const float* __restrict__ w1b, const float* __restrict__ blw,
        const float* __restrict__ blb, float* __restrict__ ws)
{
    __shared__ __align__(16) float sm[Bn * Dd];
    int t = threadIdx.x;
    for (int i = t; i < Bn * Dd; i += 256) sm[i] = meta[i];
    __syncthreads();

    if (blockIdx.x == 256) {                    // bias path: bm
        int o = t;
        float a0 = blb[o], a1 = a0, a2 = a0, a3 = a0;
        const float* wr = blw + (size_t)o * Dd;
        for (int d = 0; d < Dd; d += 4) {
            float4 wv = *(const float4*)(wr + d);
            a0 += wv.x*sm[0*Dd+d] + wv.y*sm[0*Dd+d+1] + wv.z*sm[0*Dd+d+2] + wv.w*sm[0*Dd+d+3];
            a1 += wv.x*sm[1*Dd+d] + wv.y*sm[1*Dd+d+1] + wv.z*sm[1*Dd+d+2] + wv.w*sm[1*Dd+d+3];
            a2 += wv.x*sm[2*Dd+d] + wv.y*sm[2*Dd+d+1] + wv.z*sm[2*Dd+d+2] + wv.w*sm[2*Dd+d+3];
            a3 += wv.x*sm[3*Dd+d] + wv.y*sm[3*Dd+d+1] + wv.z*sm[3*Dd+d+2] + wv.w*sm[3*Dd+d+3];
        }
        ws[BM_OFF + 0*OUTCc + o] = a0;
        ws[BM_OFF + 1*OUTCc + o] = a1;
        ws[BM_OFF + 2*OUTCc + o] = a2;
        ws[BM_OFF + 3*OUTCc + o] = a3;
    } else {                                    // wm1 rows, 2 thr/row
        int r  = blockIdx.x * 128 + (t >> 1);
        int dh = (t & 1) * 128;
        const float* wr = w1w + (size_t)r * Dd + dh;
        float a0 = 0.f, a1 = 0.f, a2 = 0.f, a3 = 0.f;
        for (int d = 0; d < 128; d += 4) {
            float4 wv = *(const float4*)(wr + d);
            int dd = dh + d;
            a0 += wv.x*sm[0*Dd+dd] + wv.y*sm[0*Dd+dd+1] + wv.z*sm[0*Dd+dd+2] + wv.w*sm[0*Dd+dd+3];
            a1 += wv.x*sm[1*Dd+dd] + wv.y*sm[1*Dd+dd+1] + wv.z*sm[1*Dd+dd+2] + wv.w*sm[1*Dd+dd+3];
            a2 += wv.x*sm[2*Dd+dd] + wv.y*sm[2*Dd+dd+1] + wv.z*sm[2*Dd+dd+2] + wv.w*sm[2*Dd+dd+3];
            a3 += wv.x*sm[3*Dd+dd] + wv.y*sm[3*Dd+dd+1] + wv.z*sm[3*Dd+dd+2] + wv.w*sm[3*Dd+dd+3];
        }
        a0 += __shfl_xor(a0, 1); a1 += __shfl_xor(a1, 1);
        a2 += __shfl_xor(a2, 1); a3 += __shfl_xor(a3, 1);
        if ((t & 1) == 0) {
            float bias = w1b[r];
            ws[WM1_OFF + 0*INCc*Dd + r] = a0 + bias;
            ws[WM1_OFF + 1*INCc*Dd + r] = a1 + bias;
            ws[WM1_OFF + 2*INCc*Dd + r] = a2 + bias;
            ws[WM1_OFF + 3*INCc*Dd + r] = a3 + bias;
        }
    }
}

// ---------------------------------------------------------------------------
// Kernel 2: per-sample GEMM  C[c,j] = wm1[b][c,:] . w2_w[j,:]  (+ w2_b[j])
// epilogue: split to bf16 hi/lo, scatter into chunked MFMA A layout:
//   k = n*128 + c ; kc = k>>5 ; kk = k&31 ; row r = (o&63)*4 + (o>>6)
//   Whi[((b*36+kc)*256 + r)*32 + kk]
// ---------------------------------------------------------------------------
__global__ void __launch_bounds__(256)
k_w2(const float* __restrict__ w2w, const float* __restrict__ w2b,
     const float* __restrict__ ws, u16* __restrict__ whi, u16* __restrict__ wlo)
{
    int bid = blockIdx.x;
    int b   = bid / 72;
    int r   = bid % 72;
    int mt  = r / 36, nt = r % 36;
    int c0  = mt * 64, j0 = nt * 64;

    __shared__ __align__(16) float At[32][68];
    __shared__ __align__(16) float Bt[32][68];

    const float* A = ws + WM1_OFF + (size_t)b * INCc * Dd;  // [128][256]
    int t  = threadIdx.x;
    int ty = t >> 4, tx = t & 15;
    int lr = t >> 2;
    int lf = t & 3;

    float acc[4][4];
#pragma unroll
    for (int i = 0; i < 4; i++)
#pragma unroll
        for (int q = 0; q < 4; q++) acc[i][q] = 0.f;

    for (int dk = 0; dk < Dd; dk += 32) {
        __syncthreads();
#pragma unroll
        for (int s = 0; s < 2; s++) {
            int f4i = lf + s * 4;
            float4 av = *(const float4*)(A + (size_t)(c0 + lr) * Dd + dk + f4i * 4);
            At[f4i*4+0][lr] = av.x; At[f4i*4+1][lr] = av.y;
            At[f4i*4+2][lr] = av.z; At[f4i*4+3][lr] = av.w;
            float4 bv = *(const float4*)(w2w + (size_t)(j0 + lr) * Dd + dk + f4i * 4);
            Bt[f4i*4+0][lr] = bv.x; Bt[f4i*4+1][lr] = bv.y;
            Bt[f4i*4+2][lr] = bv.z; Bt[f4i*4+3][lr] = bv.w;
        }
        __syncthreads();
#pragma unroll 4
        for (int d = 0; d < 32; d++) {
            float4 a4 = *(const float4*)&At[d][ty * 4];
            float4 b4 = *(const float4*)&Bt[d][tx * 4];
            acc[0][0] += a4.x*b4.x; acc[0][1] += a4.x*b4.y; acc[0][2] += a4.x*b4.z; acc[0][3] += a4.x*b4.w;
            acc[1][0] += a4.y*b4.x; acc[1][1] += a4.y*b4.y; acc[1][2] += a4.y*b4.z; acc[1][3] += a4.y*b4.w;
            acc[2][0] += a4.z*b4.x; acc[2][1] += a4.z*b4.y; acc[2][2] += a4.z*b4.z; acc[2][3] += a4.z*b4.w;
            acc[3][0] += a4.w*b4.x; acc[3][1] += a4.w*b4.y; acc[3][2] += a4.w*b4.z; acc[3][3] += a4.w*b4.w;
        }
    }

#pragma unroll
    for (int i = 0; i < 4; i++) {
        int c = c0 + ty * 4 + i;
#pragma unroll
        for (int q = 0; q < 4; q++) {
            int j = j0 + tx * 4 + q;
            int o = j / 9, n = j - o * 9;
            float v = acc[i][q] + w2b[j];
            int k  = n * 128 + c;
            int kc = k >> 5, kk = k & 31;
            int rr = ((o & 63) << 2) | (o >> 6);
            size_t e = ((size_t)(b * NCHUNK + kc) * 256 + rr) * 32 + kk;
            unsigned hu, lu;
            splitbf(v, hu, lu);
            whi[e] = (u16)hu;
            wlo[e] = (u16)lu;
        }
    }
}

// ---------------------------------------------------------------------------
// Kernel 3: deformable sampling -> bf16 split X (LDS, double-buffered) ;
//           A-frags (W hi/lo) straight from L2 ; 3-way split-precision MFMA ;
//           in-register LSTM epilogue (gate-interleaved rows).
// Block = 256 thr = 4 waves; block tile = 256 o x 32 px ; grid 512.
// ---------------------------------------------------------------------------
__global__ void __launch_bounds__(256)
k_main(const float* __restrict__ xin, const float* __restrict__ hcur,
       const float* __restrict__ ccur, const float* __restrict__ moff,
       const float* __restrict__ pw, const float* __restrict__ pb,
       const float* __restrict__ ws, const u16* __restrict__ whi,
       const u16* __restrict__ wlo, float* __restrict__ out)
{
    int bid  = blockIdx.x;
    int xcd  = bid & 7;
    int b    = xcd >> 1;                      // 2 XCD slots per sample
    int tile = ((bid >> 3) << 1) + (xcd & 1); // 0..127
    int h    = tile >> 1;
    int w0   = (tile & 1) * 32;

    __shared__ __align__(16) int   sIdx[NT][4][32];
    __shared__ __align__(16) float sWgt[NT][4][32];
    __shared__ __align__(16) u16   Xh[2][32][40];   // [buf][px][32k + 8 pad]
    __shared__ __align__(16) u16   Xl[2][32][40];
    __shared__ float bmS[OUTCc];

    int t = threadIdx.x;
    bmS[t] = ws[BM_OFF + b * OUTCc + t];

    // ---- phase 0: offsets (p_conv inline) + bilinear tables per (px, n) ----
    {
        int px   = t & 31;
        int nh   = t >> 5;
        int wpos = w0 + px;
        for (int n = nh; n < NT; n += 8) {
            float ox = pb[n], oy = pb[NT + n];
#pragma unroll
            for (int ii = 0; ii < 3; ii++) {
#pragma unroll
                for (int jj = 0; jj < 3; jj++) {
                    int rr = h - 1 + ii, cc = wpos - 1 + jj;
                    float m = (rr >= 0 && rr < 64 && cc >= 0 && cc < 64)
                              ? moff[(size_t)b * HWn + rr * 64 + cc] : 0.f;
                    ox = fmaf(pw[(size_t)n * 9 + ii * 3 + jj], m, ox);
                    oy = fmaf(pw[(size_t)(NT + n) * 9 + ii * 3 + jj], m, oy);
                }
            }
            float pr = (float)(h + (n / 3)) + ox;
            float pc = (float)(wpos + (n % 3)) + oy;
            float fr = floorf(pr), fc = floorf(pc);
            float ltr = fminf(fmaxf(fr, 0.f), 65.f);
            float ltc = fminf(fmaxf(fc, 0.f), 65.f);
            float rbr = fminf(fmaxf(fr + 1.f, 0.f), 65.f);
            float rbc = fminf(fmaxf(fc + 1.f, 0.f), 65.f);
            float cpr = fminf(fmaxf(pr, 0.f), 65.f);
            float cpc = fminf(fmaxf(pc, 0.f), 65.f);
            float ar = 1.f + ltr - cpr, br = 1.f - rbr + cpr;
            float ac = 1.f + ltc - cpc, bc = 1.f - rbc + cpc;
            int ir0 = (int)ltr, ic0 = (int)ltc, ir1 = (int)rbr, ic1 = (int)rbc;
            int   rr4[4] = {ir0, ir1, ir0, ir1};
            int   cc4[4] = {ic0, ic1, ic1, ic0};
            float gg4[4] = {ar * ac, br * bc, ar * bc, br * ac};
#pragma unroll
            for (int jj = 0; jj < 4; jj++) {
                bool inb = (rr4[jj] >= 1) && (rr4[jj] <= 64) &&
                           (cc4[jj] >= 1) && (cc4[jj] <= 64);
                sIdx[n][jj][px] = inb ? ((rr4[jj] - 1) * 64 + (cc4[jj] - 1)) : 0;
                sWgt[n][jj][px] = inb ? gg4[jj] : 0.f;
            }
        }
    }
    __syncthreads();

    int px   = t & 31;          // sampling: pixel
    int cg   = t >> 5;          // sampling: 4-channel group 0..7
    int lane = t & 63;
    int wv   = t >> 6;          // wave 0..3 -> o rows [wv*64, wv*64+64)
    int col  = lane & 15;
    int quad = lane >> 4;

    auto sample_chunk = [&](int KC, int BUF) {
        int n_ = KC >> 2;
        int c_ = ((KC & 3) << 5) + (cg << 2);
        const float* pl = (c_ < HIDc)
            ? (xin  + (size_t)(b * HIDc + c_) * HWn)
            : (hcur + (size_t)(b * HIDc + (c_ - HIDc)) * HWn);
        int   i0 = sIdx[n_][0][px], i1 = sIdx[n_][1][px],
              i2 = sIdx[n_][2][px], i3 = sIdx[n_][3][px];
        float g0 = sWgt[n_][0][px], g1 = sWgt[n_][1][px],
              g2 = sWgt[n_][2][px], g3 = sWgt[n_][3][px];
        unsigned hp0 = 0, hp1 = 0, lp0 = 0, lp1 = 0;
#pragma unroll
        for (int s = 0; s < 4; s++) {
            const float* p = pl + s * HWn;
            float v = g0 * p[i0] + g1 * p[i1] + g2 * p[i2] + g3 * p[i3];
            unsigned hu, lu;
            splitbf(v, hu, lu);
            if (s < 2) { hp0 |= hu << (16 * s);       lp0 |= lu << (16 * s); }
            else       { hp1 |= hu << (16 * (s - 2)); lp1 |= lu << (16 * (s - 2)); }
        }
        *(uint2*)&Xh[BUF][px][cg * 4] = make_uint2(hp0, hp1);
        *(uint2*)&Xl[BUF][px][cg * 4] = make_uint2(lp0, lp1);
    };

    f4 acc[4][2];
#pragma unroll
    for (int oi = 0; oi < 4; oi++)
#pragma unroll
        for (int pj = 0; pj < 2; pj++) acc[oi][pj] = (f4){0.f, 0.f, 0.f, 0.f};

    // A-frag element base (per lane): ((b*36+kc)*256 + wv*64 + oi*16 + col)*32 + quad*8
    size_t abase0 = (((size_t)b * NCHUNK) * 256 + wv * 64 + col) * 32 + quad * 8;

    sample_chunk(0, 0);
    __syncthreads();

    for (int kc = 0; kc < NCHUNK; kc++) {
        int cur = kc & 1;
        size_t ab = abase0 + (size_t)kc * 8192;
        bs8 Ah[4], Al[4];
#pragma unroll
        for (int oi = 0; oi < 4; oi++) {
            Ah[oi] = *(const bs8*)(whi + ab + oi * 512);
            Al[oi] = *(const bs8*)(wlo + ab + oi * 512);
        }
        bs8 Bh[2], Bl[2];
#pragma unroll
        for (int pj = 0; pj < 2; pj++) {
            Bh[pj] = *(const bs8*)&Xh[cur][pj * 16 + col][quad * 8];
            Bl[pj] = *(const bs8*)&Xl[cur][pj * 16 + col][quad * 8];
        }
        if (kc < NCHUNK - 1) sample_chunk(kc + 1, cur ^ 1);
#pragma unroll
        for (int oi = 0; oi < 4; oi++)
#pragma unroll
            for (int pj = 0; pj < 2; pj++) {
                acc[oi][pj] = __builtin_amdgcn_mfma_f32_16x16x32_bf16(Ah[oi], Bh[pj], acc[oi][pj], 0, 0, 0);
                acc[oi][pj] = __builtin_amdgcn_mfma_f32_16x16x32_bf16(Ah[oi], Bl[pj], acc[oi][pj], 0, 0, 0);
                acc[oi][pj] = __builtin_amdgcn_mfma_f32_16x16x32_bf16(Al[oi], Bh[pj], acc[oi][pj], 0, 0, 0);
            }
        __syncthreads();
    }

    // ---- epilogue: each C-frag reg r = gate r for ch = wv*16+oi*4+quad ----
#pragma unroll
    for (int oi = 0; oi < 4; oi++) {
        int ch = wv * 16 + oi * 4 + quad;
#pragma unroll
        for (int pj = 0; pj < 2; pj++) {
            int wpos = w0 + pj * 16 + col;
            f4 a = acc[oi][pj];
            float ci  = a[0] + bmS[ch];
            float cf  = a[1] + bmS[64 + ch];
            float co  = a[2] + bmS[128 + ch];
            float cgv = a[3] + bmS[192 + ch];
            float ig  = sigf(ci);
            float fg  = sigf(cf);
            float og_ = sigf(co);
            float gg  = tanhfast(cgv);
            size_t idx = (((size_t)(b * HIDc + ch)) * 64 + h) * 64 + wpos;
            float cp = ccur[idx];
            float cn = fg * cp + ig * gg;
            out[idx] = og_ * tanhfast(cn);                   // h_next
            out[(size_t)Bn * HIDc * HWn + idx] = cn;         // c_next
        }
    }
}

// ---------------------------------------------------------------------------
extern "C" void kernel_launch(void* const* d_in, const int* in_sizes, int n_in,
                              void* d_out, int out_size, void* d_ws, size_t ws_size,
                              hipStream_t stream)
{
    const float* xin  = (const float*)d_in[0];
    const float* hcur = (const float*)d_in[1];
    const float* ccur = (const float*)d_in[2];
    const float* meta = (const float*)d_in[3];
    const float* moff = (const float*)d_in[4];
    const float* w1w  = (const float*)d_in[5];
    const float* w1b  = (const float*)d_in[6];
    const float* w2w  = (const float*)d_in[7];
    const float* w2b  = (const float*)d_in[8];
    const float* blw  = (const float*)d_in[9];
    const float* blb  = (const float*)d_in[10];
    const float* pw   = (const float*)d_in[11];
    const float* pb   = (const float*)d_in[12];
    float* out = (float*)d_out;
    float* ws  = (float*)d_ws;
    u16*   whi = (u16*)((char*)d_ws + WSPLIT_BYTE);
    u16*   wlo = whi + WPLANE;

    hipLaunchKernelGGL(k_hyper, dim3(257), dim3(256), 0, stream,
                       meta, w1w, w1b, blw, blb, ws);
    hipLaunchKernelGGL(k_w2, dim3(288), dim3(256), 0, stream, w2w, w2b, ws, whi, wlo);
    hipLaunchKernelGGL(k_main, dim3(512), dim3(256), 0, stream,
                       xin, hcur, ccur, moff, pw, pb, ws, whi, wlo, out);
}

// Round 4
// 184.074 us; speedup vs baseline: 1.5800x; 1.1732x over previous
//
#include <hip/hip_runtime.h>
#include <math.h>

#define Bn    4
#define HIDc  64          // hidden / input channels each = 64
#define INCc  128         // concat channels
#define OUTCc 256         // 4*HID gates
#define Dd    256         // meta dim
#define NT    9           // K*K taps
#define HWn   4096        // 64*64
#define NC    18          // K=1152 in 64-chunks, k = n*128 + c

typedef _Float16 f16;
typedef unsigned short u16;
typedef __attribute__((ext_vector_type(8))) _Float16 h8;   // 8 fp16 (4 VGPRs)
typedef __attribute__((ext_vector_type(4))) float f4;      // MFMA C/D frag

// ---- workspace layout ----
// floats: wm1 [B][INC*D] = 131072 ; bm [B][OUTC] = 1024
// f16:    TX  [B][4096 pos][128 ch]            (channel-last input copy)
//         WH  [B][18 kc][256 r][64 kk]         (r = (o&63)*4 + (o>>6))
#define WM1_OFF 0
#define BM_OFF  (Bn*INCc*Dd)
#define F16_BYTE_OFF ((size_t)(BM_OFF + Bn*OUTCc) * 4)
#define TX_ELEMS ((size_t)Bn*HWn*INCc)

__device__ __forceinline__ float sigf(float x) { return 1.f / (1.f + __expf(-x)); }
__device__ __forceinline__ float tanhfast(float x) {
    float a = fabsf(x);
    float e = __expf(2.f * a);
    float t = 1.f - 2.f / (e + 1.f);
    return copysignf(t, x);
}

// ---------------------------------------------------------------------------
// Kernel 0: channel-last fp16 copy  TX[b][h*64+w][c] = cvt(x||h)[b][c][h][w]
// grid 256 = (b,h); coalesced reads (64 w per wave per plane), b128 stores.
// BUG FIX vs R3: s loop now covers all 16 octets (128 channels), not 8.
// ---------------------------------------------------------------------------
__global__ void __launch_bounds__(256)
k_tr(const float* __restrict__ xin, const float* __restrict__ hcur,
     f16* __restrict__ tx)
{
    int b = blockIdx.x >> 6, h = blockIdx.x & 63;
    int t = threadIdx.x;
    int w = t & 63, oq = t >> 6;              // oq 0..3
    const float* xb = xin  + ((size_t)b * HIDc) * HWn + h * 64;
    const float* hb = hcur + ((size_t)b * HIDc) * HWn + h * 64;
    f16* dst = tx + ((size_t)(b * HWn + h * 64 + w)) * INCc;
#pragma unroll
    for (int s = 0; s < 4; s++) {
        int c0 = (oq + s * 4) * 8;            // octet base channel, 0..120
        h8 v;
#pragma unroll
        for (int i = 0; i < 8; i++) {
            int ci = c0 + i;
            float f = (ci < HIDc) ? xb[(size_t)ci * HWn + w]
                                  : hb[(size_t)(ci - HIDc) * HWn + w];
            v[i] = (f16)f;
        }
        *(h8*)(dst + c0) = v;
    }
}

// ---------------------------------------------------------------------------
// Kernel 1: wm1 rows (33024 = 32768 w1 + 256 bl), coalesced.
// grid 516 x 256 thr; wave handles 16 rows as 4 groups of 4; lane = (row4, d16).
// ---------------------------------------------------------------------------
__global__ void __launch_bounds__(256)
k_hyper(const float* __restrict__ meta, const float* __restrict__ w1w,
        const float* __restrict__ w1b, const float* __restrict__ blw,
        const float* __restrict__ blb, float* __restrict__ ws)
{
    __shared__ __align__(16) float sm[Bn * Dd];
    int t = threadIdx.x;
    for (int i = t; i < Bn * Dd; i += 256) sm[i] = meta[i];
    __syncthreads();

    int lane = t & 63, wvv = t >> 6;
    int rl = lane >> 4, dl = lane & 15;
    int rbase = blockIdx.x * 64 + wvv * 16;

#pragma unroll
    for (int g = 0; g < 4; g++) {
        int r = rbase + g * 4 + rl;
        bool isbl = (r >= INCc * Dd);
        const float* row = isbl ? (blw + (size_t)(r - INCc * Dd) * Dd)
                                : (w1w + (size_t)r * Dd);
        float a0 = 0.f, a1 = 0.f, a2 = 0.f, a3 = 0.f;
#pragma unroll
        for (int it = 0; it < 4; it++) {
            int d = it * 64 + dl * 4;
            float4 wv = *(const float4*)(row + d);
            float4 m0 = *(const float4*)&sm[0 * Dd + d];
            float4 m1 = *(const float4*)&sm[1 * Dd + d];
            float4 m2 = *(const float4*)&sm[2 * Dd + d];
            float4 m3 = *(const float4*)&sm[3 * Dd + d];
            a0 += wv.x*m0.x + wv.y*m0.y + wv.z*m0.z + wv.w*m0.w;
            a1 += wv.x*m1.x + wv.y*m1.y + wv.z*m1.z + wv.w*m1.w;
            a2 += wv.x*m2.x + wv.y*m2.y + wv.z*m2.z + wv.w*m2.w;
            a3 += wv.x*m3.x + wv.y*m3.y + wv.z*m3.z + wv.w*m3.w;
        }
#pragma unroll
        for (int mk = 1; mk <= 8; mk <<= 1) {
            a0 += __shfl_xor(a0, mk); a1 += __shfl_xor(a1, mk);
            a2 += __shfl_xor(a2, mk); a3 += __shfl_xor(a3, mk);
        }
        if (dl == 0) {
            if (isbl) {
                int rb = r - INCc * Dd;
                float bb = blb[rb];
                ws[BM_OFF + 0*OUTCc + rb] = a0 + bb;
                ws[BM_OFF + 1*OUTCc + rb] = a1 + bb;
                ws[BM_OFF + 2*OUTCc + rb] = a2 + bb;
                ws[BM_OFF + 3*OUTCc + rb] = a3 + bb;
            } else {
                float bb = w1b[r];
                ws[WM1_OFF + 0*INCc*Dd + r] = a0 + bb;
                ws[WM1_OFF + 1*INCc*Dd + r] = a1 + bb;
                ws[WM1_OFF + 2*INCc*Dd + r] = a2 + bb;
                ws[WM1_OFF + 3*INCc*Dd + r] = a3 + bb;
            }
        }
    }
}

// ---------------------------------------------------------------------------
// Kernel 2: per-sample GEMM  Wk[c,j] = wm1[b][c,:] . w2_w[j,:] + w2_b[j]
// 32c x 64j tiles, 576 blocks (2.25 blk/CU); epilogue: fp16 RN scatter into
// MFMA A layout: k = n*128+c ; kc=k>>6 ; kk=k&63 ; r = (o&63)*4 + (o>>6)
// ---------------------------------------------------------------------------
__global__ void __launch_bounds__(256)
k_w2(const float* __restrict__ w2w, const float* __restrict__ w2b,
     const float* __restrict__ ws, f16* __restrict__ wh)
{
    int bid = blockIdx.x;
    int b   = bid / 144;
    int r   = bid % 144;
    int mt  = r / 36, nt = r % 36;
    int c0  = mt * 32, j0 = nt * 64;

    __shared__ __align__(16) float At[32][34];   // [d][c]
    __shared__ __align__(16) float Bt[32][68];   // [d][j]

    const float* A = ws + WM1_OFF + (size_t)b * INCc * Dd;
    int t   = threadIdx.x;
    int lrA = t >> 3, lfA = t & 7;
    int lrB = t >> 2, lfB = t & 3;
    int ty  = t >> 4, tx = t & 15;

    float acc[2][4];
#pragma unroll
    for (int i = 0; i < 2; i++)
#pragma unroll
        for (int q = 0; q < 4; q++) acc[i][q] = 0.f;

    for (int dk = 0; dk < Dd; dk += 32) {
        __syncthreads();
        {
            float4 av = *(const float4*)(A + (size_t)(c0 + lrA) * Dd + dk + lfA * 4);
            At[lfA*4+0][lrA] = av.x; At[lfA*4+1][lrA] = av.y;
            At[lfA*4+2][lrA] = av.z; At[lfA*4+3][lrA] = av.w;
        }
#pragma unroll
        for (int s = 0; s < 2; s++) {
            int f = lfB + s * 4;
            float4 bv = *(const float4*)(w2w + (size_t)(j0 + lrB) * Dd + dk + f * 4);
            Bt[f*4+0][lrB] = bv.x; Bt[f*4+1][lrB] = bv.y;
            Bt[f*4+2][lrB] = bv.z; Bt[f*4+3][lrB] = bv.w;
        }
        __syncthreads();
#pragma unroll 4
        for (int d = 0; d < 32; d++) {
            float2 a2 = *(const float2*)&At[d][ty * 2];
            float4 b4 = *(const float4*)&Bt[d][tx * 4];
            acc[0][0] += a2.x*b4.x; acc[0][1] += a2.x*b4.y;
            acc[0][2] += a2.x*b4.z; acc[0][3] += a2.x*b4.w;
            acc[1][0] += a2.y*b4.x; acc[1][1] += a2.y*b4.y;
            acc[1][2] += a2.y*b4.z; acc[1][3] += a2.y*b4.w;
        }
    }

#pragma unroll
    for (int i = 0; i < 2; i++) {
        int c = c0 + ty * 2 + i;
#pragma unroll
        for (int q = 0; q < 4; q++) {
            int j = j0 + tx * 4 + q;
            int o = j / 9, n = j - o * 9;
            float v = acc[i][q] + w2b[j];
            int k  = n * 128 + c;
            int kc = k >> 6, kk = k & 63;
            int rr = ((o & 63) << 2) | (o >> 6);
            wh[((size_t)(b * NC + kc) * 256 + rr) * 64 + kk] = (f16)v;
        }
    }
}

// ---------------------------------------------------------------------------
// Kernel 3: deformable sampling (8-ch b128 gathers from TX) -> fp16 X in
// XOR-swizzled LDS (double-buffered); fp16 A-frags from L2; single-plane
// fp16 MFMA; in-register LSTM epilogue (gate-interleaved rows).
// Block = 256 thr = 4 waves; tile = 256 o x 32 px; grid 512 (2 blk/CU).
// ---------------------------------------------------------------------------
__global__ void __launch_bounds__(256)
k_main(const f16* __restrict__ tx, const float* __restrict__ ccur,
       const float* __restrict__ moff, const float* __restrict__ pw,
       const float* __restrict__ pb, const float* __restrict__ ws,
       const f16* __restrict__ wh, float* __restrict__ out)
{
    int bid  = blockIdx.x;
    int xcd  = bid & 7;
    int b    = xcd >> 1;                      // 2 XCD slots per sample
    int tile = ((bid >> 3) << 1) + (xcd & 1); // 0..127
    int h    = tile >> 1;
    int w0   = (tile & 1) * 32;

    __shared__ __align__(16) int   sIdx[NT][4][32];
    __shared__ __align__(16) float sWgt[NT][4][32];
    __shared__ __align__(16) f16   Xs[2][32][64];   // XOR-swizzled 16B granules
    __shared__ float bmS[OUTCc];

    int t = threadIdx.x;
    bmS[t] = ws[BM_OFF + b * OUTCc + t];

    // ---- phase 0: offsets (p_conv inline) + bilinear tables per (px, n) ----
    {
        int px   = t & 31;
        int nh   = t >> 5;
        int wpos = w0 + px;
        for (int n = nh; n < NT; n += 8) {
            float ox = pb[n], oy = pb[NT + n];
#pragma unroll
            for (int ii = 0; ii < 3; ii++) {
#pragma unroll
                for (int jj = 0; jj < 3; jj++) {
                    int rr = h - 1 + ii, cc = wpos - 1 + jj;
                    float m = (rr >= 0 && rr < 64 && cc >= 0 && cc < 64)
                              ? moff[(size_t)b * HWn + rr * 64 + cc] : 0.f;
                    ox = fmaf(pw[(size_t)n * 9 + ii * 3 + jj], m, ox);
                    oy = fmaf(pw[(size_t)(NT + n) * 9 + ii * 3 + jj], m, oy);
                }
            }
            float pr = (float)(h + (n / 3)) + ox;
            float pc = (float)(wpos + (n % 3)) + oy;
            float fr = floorf(pr), fc = floorf(pc);
            float ltr = fminf(fmaxf(fr, 0.f), 65.f);
            float ltc = fminf(fmaxf(fc, 0.f), 65.f);
            float rbr = fminf(fmaxf(fr + 1.f, 0.f), 65.f);
            float rbc = fminf(fmaxf(fc + 1.f, 0.f), 65.f);
            float cpr = fminf(fmaxf(pr, 0.f), 65.f);
            float cpc = fminf(fmaxf(pc, 0.f), 65.f);
            float ar = 1.f + ltr - cpr, br = 1.f - rbr + cpr;
            float ac = 1.f + ltc - cpc, bc = 1.f - rbc + cpc;
            int ir0 = (int)ltr, ic0 = (int)ltc, ir1 = (int)rbr, ic1 = (int)rbc;
            int   rr4[4] = {ir0, ir1, ir0, ir1};
            int   cc4[4] = {ic0, ic1, ic1, ic0};
            float gg4[4] = {ar * ac, br * bc, ar * bc, br * ac};
#pragma unroll
            for (int jj = 0; jj < 4; jj++) {
                bool inb = (rr4[jj] >= 1) && (rr4[jj] <= 64) &&
                           (cc4[jj] >= 1) && (cc4[jj] <= 64);
                sIdx[n][jj][px] = inb ? ((rr4[jj] - 1) * 64 + (cc4[jj] - 1)) : 0;
                sWgt[n][jj][px] = inb ? gg4[jj] : 0.f;
            }
        }
    }
    __syncthreads();

    int px   = t & 31;          // sampling: pixel
    int oct  = t >> 5;          // sampling: channel octet 0..7
    int lane = t & 63;
    int wv   = t >> 6;          // wave 0..3 -> o rows [wv*64, wv*64+64)
    int col  = lane & 15;
    int quad = lane >> 4;

    const f16* txb = tx + (size_t)b * HWn * INCc;

    auto sample_chunk = [&](int KC, int BUF) {
        int n_ = KC >> 1;
        int coff = ((KC & 1) << 6) + (oct << 3);
        const f16* p0 = txb + (size_t)sIdx[n_][0][px] * INCc + coff;
        const f16* p1 = txb + (size_t)sIdx[n_][1][px] * INCc + coff;
        const f16* p2 = txb + (size_t)sIdx[n_][2][px] * INCc + coff;
        const f16* p3 = txb + (size_t)sIdx[n_][3][px] * INCc + coff;
        float g0 = sWgt[n_][0][px], g1 = sWgt[n_][1][px],
              g2 = sWgt[n_][2][px], g3 = sWgt[n_][3][px];
        h8 v0 = *(const h8*)p0;
        h8 v1 = *(const h8*)p1;
        h8 v2 = *(const h8*)p2;
        h8 v3 = *(const h8*)p3;
        h8 res;
#pragma unroll
        for (int i = 0; i < 8; i++) {
            float v = g0 * (float)v0[i] + g1 * (float)v1[i]
                    + g2 * (float)v2[i] + g3 * (float)v3[i];
            res[i] = (f16)v;
        }
        *(h8*)&Xs[BUF][px][(oct ^ (px & 7)) << 3] = res;
    };

    f4 acc[4][2];
#pragma unroll
    for (int oi = 0; oi < 4; oi++)
#pragma unroll
        for (int pj = 0; pj < 2; pj++) acc[oi][pj] = (f4){0.f, 0.f, 0.f, 0.f};

    const f16* whb = wh + (size_t)b * NC * 256 * 64;

    sample_chunk(0, 0);
    __syncthreads();

    for (int kc = 0; kc < NC; kc++) {
        int cur = kc & 1;
        h8 Af[4][2];
#pragma unroll
        for (int oi = 0; oi < 4; oi++)
#pragma unroll
            for (int ks = 0; ks < 2; ks++)
                Af[oi][ks] = *(const h8*)(whb +
                    ((size_t)kc * 256 + wv * 64 + oi * 16 + col) * 64 + ks * 32 + quad * 8);
        h8 Bf[2][2];
#pragma unroll
        for (int pj = 0; pj < 2; pj++)
#pragma unroll
            for (int ks = 0; ks < 2; ks++) {
                int pxx = pj * 16 + col;
                int g   = ks * 4 + quad;
                Bf[pj][ks] = *(const h8*)&Xs[cur][pxx][(g ^ (pxx & 7)) << 3];
            }
        if (kc < NC - 1) sample_chunk(kc + 1, cur ^ 1);
#pragma unroll
        for (int oi = 0; oi < 4; oi++)
#pragma unroll
            for (int pj = 0; pj < 2; pj++) {
                acc[oi][pj] = __builtin_amdgcn_mfma_f32_16x16x32_f16(Af[oi][0], Bf[pj][0], acc[oi][pj], 0, 0, 0);
                acc[oi][pj] = __builtin_amdgcn_mfma_f32_16x16x32_f16(Af[oi][1], Bf[pj][1], acc[oi][pj], 0, 0, 0);
            }
        __syncthreads();
    }

    // ---- epilogue: C-frag reg r = gate r for ch = wv*16 + oi*4 + quad ----
#pragma unroll
    for (int oi = 0; oi < 4; oi++) {
        int ch = wv * 16 + oi * 4 + quad;
#pragma unroll
        for (int pj = 0; pj < 2; pj++) {
            int wpos = w0 + pj * 16 + col;
            f4 a = acc[oi][pj];
            float ci  = a[0] + bmS[ch];
            float cf  = a[1] + bmS[64 + ch];
            float co  = a[2] + bmS[128 + ch];
            float cgv = a[3] + bmS[192 + ch];
            float ig  = sigf(ci);
            float fg  = sigf(cf);
            float og_ = sigf(co);
            float gg  = tanhfast(cgv);
            size_t idx = (((size_t)(b * HIDc + ch)) * 64 + h) * 64 + wpos;
            float cp = ccur[idx];
            float cn = fg * cp + ig * gg;
            out[idx] = og_ * tanhfast(cn);                   // h_next
            out[(size_t)Bn * HIDc * HWn + idx] = cn;         // c_next
        }
    }
}

// ---------------------------------------------------------------------------
extern "C" void kernel_launch(void* const* d_in, const int* in_sizes, int n_in,
                              void* d_out, int out_size, void* d_ws, size_t ws_size,
                              hipStream_t stream)
{
    const float* xin  = (const float*)d_in[0];
    const float* hcur = (const float*)d_in[1];
    const float* ccur = (const float*)d_in[2];
    const float* meta = (const float*)d_in[3];
    const float* moff = (const float*)d_in[4];
    const float* w1w  = (const float*)d_in[5];
    const float* w1b  = (const float*)d_in[6];
    const float* w2w  = (const float*)d_in[7];
    const float* w2b  = (const float*)d_in[8];
    const float* blw  = (const float*)d_in[9];
    const float* blb  = (const float*)d_in[10];
    const float* pw   = (const float*)d_in[11];
    const float* pb   = (const float*)d_in[12];
    float* out = (float*)d_out;
    float* ws  = (float*)d_ws;
    f16*   tx  = (f16*)((char*)d_ws + F16_BYTE_OFF);
    f16*   wh  = tx + TX_ELEMS;

    hipLaunchKernelGGL(k_tr,    dim3(256), dim3(256), 0, stream, xin, hcur, tx);
    hipLaunchKernelGGL(k_hyper, dim3(516), dim3(256), 0, stream,
                       meta, w1w, w1b, blw, blb, ws);
    hipLaunchKernelGGL(k_w2,    dim3(576), dim3(256), 0, stream, w2w, w2b, ws, wh);
    hipLaunchKernelGGL(k_main,  dim3(512), dim3(256), 0, stream,
                       tx, ccur, moff, pw, pb, ws, wh, out);
}

// Round 6
// 152.094 us; speedup vs baseline: 1.9122x; 1.2103x over previous
//
#include <hip/hip_runtime.h>
#include <math.h>

#define Bn    4
#define HIDc  64          // hidden / input channels each = 64
#define INCc  128         // concat channels
#define OUTCc 256         // 4*HID gates
#define Dd    256         // meta dim
#define NT    9           // K*K taps
#define HWn   4096        // 64*64
#define NC    18          // K=1152 in 64-chunks, k = n*128 + c

typedef _Float16 f16;
typedef unsigned short u16;
typedef unsigned int u32;
typedef __attribute__((ext_vector_type(8))) _Float16 h8;   // 8 fp16 (4 VGPRs)
typedef __attribute__((ext_vector_type(4))) float f4;      // MFMA C/D frag

// ---- workspace layout ----
// floats: bm [B][OUTC] = 1024 floats at offset 0
// f16 region (elem offsets from byte 4096):
//   TX  [B][4096 pos][128 ch]                     2,097,152
//   WH  [B][18 kc][256 rr][8 slot][8 e]           1,179,648  (granule-swizzled)
//   M1H [B][128 c][256 d], M1L same                 131,072 each
#define BM_OFF   0
#define F16_BYTE 4096
#define TX_F   ((size_t)0)
#define WH_F   ((size_t)2097152)
#define M1H_F  ((size_t)3276800)
#define M1L_F  ((size_t)3407872)

__device__ __forceinline__ float sigf(float x) { return 1.f / (1.f + __expf(-x)); }
__device__ __forceinline__ float tanhfast(float x) {
    float a = fabsf(x);
    float e = __expf(2.f * a);
    float t = 1.f - 2.f / (e + 1.f);
    return copysignf(t, x);
}

// ---------------------------------------------------------------------------
// Kernel 0: channel-last fp16 copy  TX[b][h*64+w][c] = cvt(x||h)[b][c][h][w]
// ---------------------------------------------------------------------------
__global__ void __launch_bounds__(256)
k_tr(const float* __restrict__ xin, const float* __restrict__ hcur,
     f16* __restrict__ tx)
{
    int b = blockIdx.x >> 6, h = blockIdx.x & 63;
    int t = threadIdx.x;
    int w = t & 63, oq = t >> 6;              // oq 0..3
    const float* xb = xin  + ((size_t)b * HIDc) * HWn + h * 64;
    const float* hb = hcur + ((size_t)b * HIDc) * HWn + h * 64;
    f16* dst = tx + ((size_t)(b * HWn + h * 64 + w)) * INCc;
#pragma unroll
    for (int s = 0; s < 4; s++) {
        int c0 = (oq + s * 4) * 8;            // 0..120
        h8 v;
#pragma unroll
        for (int i = 0; i < 8; i++) {
            int ci = c0 + i;
            float f = (ci < HIDc) ? xb[(size_t)ci * HWn + w]
                                  : hb[(size_t)(ci - HIDc) * HWn + w];
            v[i] = (f16)f;
        }
        *(h8*)(dst + c0) = v;
    }
}

// ---------------------------------------------------------------------------
// Kernel 1: wm1 rows (33024 = 32768 w1 + 256 bl), coalesced 16-lane reduce.
// w1 rows -> fp16 hi/lo planes M1H/M1L ; bl rows -> bm f32.
// ---------------------------------------------------------------------------
__global__ void __launch_bounds__(256)
k_hyper(const float* __restrict__ meta, const float* __restrict__ w1w,
        const float* __restrict__ w1b, const float* __restrict__ blw,
        const float* __restrict__ blb, float* __restrict__ bm,
        f16* __restrict__ m1h, f16* __restrict__ m1l)
{
    __shared__ __align__(16) float sm[Bn * Dd];
    int t = threadIdx.x;
    for (int i = t; i < Bn * Dd; i += 256) sm[i] = meta[i];
    __syncthreads();

    int lane = t & 63, wvv = t >> 6;
    int rl = lane >> 4, dl = lane & 15;
    int rbase = blockIdx.x * 64 + wvv * 16;

#pragma unroll
    for (int g = 0; g < 4; g++) {
        int r = rbase + g * 4 + rl;
        bool isbl = (r >= INCc * Dd);
        const float* row = isbl ? (blw + (size_t)(r - INCc * Dd) * Dd)
                                : (w1w + (size_t)r * Dd);
        float a0 = 0.f, a1 = 0.f, a2 = 0.f, a3 = 0.f;
#pragma unroll
        for (int it = 0; it < 4; it++) {
            int d = it * 64 + dl * 4;
            float4 wv = *(const float4*)(row + d);
            float4 m0 = *(const float4*)&sm[0 * Dd + d];
            float4 m1 = *(const float4*)&sm[1 * Dd + d];
            float4 m2 = *(const float4*)&sm[2 * Dd + d];
            float4 m3 = *(const float4*)&sm[3 * Dd + d];
            a0 += wv.x*m0.x + wv.y*m0.y + wv.z*m0.z + wv.w*m0.w;
            a1 += wv.x*m1.x + wv.y*m1.y + wv.z*m1.z + wv.w*m1.w;
            a2 += wv.x*m2.x + wv.y*m2.y + wv.z*m2.z + wv.w*m2.w;
            a3 += wv.x*m3.x + wv.y*m3.y + wv.z*m3.z + wv.w*m3.w;
        }
#pragma unroll
        for (int mk = 1; mk <= 8; mk <<= 1) {
            a0 += __shfl_xor(a0, mk); a1 += __shfl_xor(a1, mk);
            a2 += __shfl_xor(a2, mk); a3 += __shfl_xor(a3, mk);
        }
        if (dl == 0) {
            if (isbl) {
                int rb = r - INCc * Dd;
                float bb = blb[rb];
                bm[0*OUTCc + rb] = a0 + bb;
                bm[1*OUTCc + rb] = a1 + bb;
                bm[2*OUTCc + rb] = a2 + bb;
                bm[3*OUTCc + rb] = a3 + bb;
            } else {
                float bb = w1b[r];
                float v[4] = {a0 + bb, a1 + bb, a2 + bb, a3 + bb};
#pragma unroll
                for (int bi = 0; bi < 4; bi++) {
                    f16 hi = (f16)v[bi];
                    f16 lo = (f16)(v[bi] - (float)hi);
                    m1h[(size_t)bi * 32768 + r] = hi;
                    m1l[(size_t)bi * 32768 + r] = lo;
                }
            }
        }
    }
}

// ---------------------------------------------------------------------------
// Kernel 2: per-sample hyper GEMM via fp16 MFMA, A = wm1 (hi/lo split),
// B = w2_w (fp16 RN, converted during staging). K=256 fully LDS-resident,
// ONE barrier. Tile 32c x 64j, 576 blocks.
// BUG FIX vs R5: LDS tiles were [.][136] with K=256 writes (OOB trample).
// Now stride-256 rows + granule-XOR swizzle (g -> g^(row&7)), 64 KB total.
// Epilogue scatters into WH with slot = (kk>>3) ^ (rr&7).
// ---------------------------------------------------------------------------
__global__ void __launch_bounds__(256)
k_w2(const float* __restrict__ w2w, const float* __restrict__ w2b,
     const f16* __restrict__ m1h, const f16* __restrict__ m1l,
     f16* __restrict__ wh)
{
    int bid = blockIdx.x;
    int b   = bid / 144;
    int rem = bid % 144;
    int c0  = (rem / 36) * 32;
    int j0  = (rem % 36) * 64;

    __shared__ __align__(16) f16 Ah[32][256];   // granule-XOR swizzled
    __shared__ __align__(16) f16 Al[32][256];
    __shared__ __align__(16) f16 Bh[64][256];

    int t = threadIdx.x;
    {   // stage A (hi/lo): row 0..31, seg 0..7 -> granules seg*4+i (i<4)
        int row = t >> 3, seg = t & 7;
        const f16* sh = m1h + (size_t)b * 32768 + (size_t)(c0 + row) * 256 + seg * 32;
        const f16* sl = m1l + (size_t)b * 32768 + (size_t)(c0 + row) * 256 + seg * 32;
#pragma unroll
        for (int i = 0; i < 4; i++) {
            int gsl = ((seg * 4 + i) ^ (row & 7)) * 8;
            *(h8*)&Ah[row][gsl] = *(const h8*)(sh + i * 8);
            *(h8*)&Al[row][gsl] = *(const h8*)(sl + i * 8);
        }
        // stage B (fp32 -> fp16 convert): row2 0..63, seg2 0..3 -> granules seg2*8+i
        int row2 = t >> 2, seg2 = t & 3;
        const float* sb = w2w + (size_t)(j0 + row2) * 256 + seg2 * 64;
#pragma unroll
        for (int i = 0; i < 8; i++) {
            float4 x0 = *(const float4*)(sb + i * 8);
            float4 x1 = *(const float4*)(sb + i * 8 + 4);
            h8 v = {(f16)x0.x, (f16)x0.y, (f16)x0.z, (f16)x0.w,
                    (f16)x1.x, (f16)x1.y, (f16)x1.z, (f16)x1.w};
            *(h8*)&Bh[row2][((seg2 * 8 + i) ^ (row2 & 7)) * 8] = v;
        }
    }
    __syncthreads();

    int lane = t & 63, jw = t >> 6;
    int col = lane & 15, quad = lane >> 4;

    f4 acc[2];
    acc[0] = (f4){0.f, 0.f, 0.f, 0.f};
    acc[1] = (f4){0.f, 0.f, 0.f, 0.f};
#pragma unroll
    for (int ks = 0; ks < 8; ks++) {
        int gsl = ((ks * 4 + quad) ^ (col & 7)) * 8;   // granule ks*4+quad, XOR row&7
        h8 Bf = *(const h8*)&Bh[jw * 16 + col][gsl];
#pragma unroll
        for (int cf = 0; cf < 2; cf++) {
            h8 Ahf = *(const h8*)&Ah[cf * 16 + col][gsl];
            h8 Alf = *(const h8*)&Al[cf * 16 + col][gsl];
            acc[cf] = __builtin_amdgcn_mfma_f32_16x16x32_f16(Ahf, Bf, acc[cf], 0, 0, 0);
            acc[cf] = __builtin_amdgcn_mfma_f32_16x16x32_f16(Alf, Bf, acc[cf], 0, 0, 0);
        }
    }

    int j = j0 + jw * 16 + col;
    int o = j / 9, n = j - o * 9;
    float bias = w2b[j];
    int rr = ((o & 63) << 2) | (o >> 6);
    f16* whb = wh + (size_t)b * (NC * 16384);
#pragma unroll
    for (int cf = 0; cf < 2; cf++)
#pragma unroll
        for (int rg = 0; rg < 4; rg++) {
            int c  = c0 + cf * 16 + quad * 4 + rg;
            int k  = n * 128 + c;
            int kc = k >> 6, kk = k & 63;
            int slot = (kk >> 3) ^ (rr & 7);
            whb[((size_t)kc * 256 + rr) * 64 + slot * 8 + (kk & 7)] =
                (f16)(acc[cf][rg] + bias);
        }
}

// ---------------------------------------------------------------------------
// Kernel 3: 512 thr / 8 waves, 64 px (full h-row) x 256 o per block, 256
// blocks (1/CU). W chunk (32 KB) staged via async global_load_lds into a
// SINGLE LDS buffer; X sampled into single 8 KB buffer; per chunk:
// frag ds_reads -> regs, barrier, overwrite (DMA + sample kc+1), MFMA,
// barrier. Granule-XOR swizzle keeps all LDS at the BW floor.
// ---------------------------------------------------------------------------
__global__ void __launch_bounds__(512)
k_main(const f16* __restrict__ tx, const float* __restrict__ ccur,
       const float* __restrict__ moff, const float* __restrict__ pw,
       const float* __restrict__ pb, const float* __restrict__ bm,
       const f16* __restrict__ wh, float* __restrict__ out)
{
    int bid = blockIdx.x;
    int xcd = bid & 7;
    int b   = xcd >> 1;                       // 2 XCD slots per sample
    int h   = ((bid >> 3) << 1) | (xcd & 1);  // 0..63

    __shared__ u16   sIdx[NT][4][64];
    __shared__ float sWgt[NT][4][64];
    __shared__ __align__(16) f16 Wb[256 * 64];   // 32 KB, granule-swizzled
    __shared__ __align__(16) f16 Xs[64][64];     // 8 KB, granule-swizzled
    __shared__ float bmS[OUTCc];

    int t = threadIdx.x;
    if (t < 256) bmS[t] = bm[b * OUTCc + t];

    // ---- phase 0: offset conv + bilinear tables for 64 px x 9 taps ----
    {
        int px = t & 63;
        int nh = t >> 6;                      // 0..7
        for (int n = nh; n < NT; n += 8) {
            float ox = pb[n], oy = pb[NT + n];
#pragma unroll
            for (int ii = 0; ii < 3; ii++) {
#pragma unroll
                for (int jj = 0; jj < 3; jj++) {
                    int rr = h - 1 + ii, cc = px - 1 + jj;
                    float m = (rr >= 0 && rr < 64 && cc >= 0 && cc < 64)
                              ? moff[(size_t)b * HWn + rr * 64 + cc] : 0.f;
                    ox = fmaf(pw[(size_t)n * 9 + ii * 3 + jj], m, ox);
                    oy = fmaf(pw[(size_t)(NT + n) * 9 + ii * 3 + jj], m, oy);
                }
            }
            float pr = (float)(h + (n / 3)) + ox;
            float pc = (float)(px + (n % 3)) + oy;
            float fr = floorf(pr), fc = floorf(pc);
            float ltr = fminf(fmaxf(fr, 0.f), 65.f);
            float ltc = fminf(fmaxf(fc, 0.f), 65.f);
            float rbr = fminf(fmaxf(fr + 1.f, 0.f), 65.f);
            float rbc = fminf(fmaxf(fc + 1.f, 0.f), 65.f);
            float cpr = fminf(fmaxf(pr, 0.f), 65.f);
            float cpc = fminf(fmaxf(pc, 0.f), 65.f);
            float ar = 1.f + ltr - cpr, br = 1.f - rbr + cpr;
            float ac = 1.f + ltc - cpc, bc = 1.f - rbc + cpc;
            int ir0 = (int)ltr, ic0 = (int)ltc, ir1 = (int)rbr, ic1 = (int)rbc;
            int   rr4[4] = {ir0, ir1, ir0, ir1};
            int   cc4[4] = {ic0, ic1, ic1, ic0};
            float gg4[4] = {ar * ac, br * bc, ar * bc, br * ac};
#pragma unroll
            for (int jj = 0; jj < 4; jj++) {
                bool inb = (rr4[jj] >= 1) && (rr4[jj] <= 64) &&
                           (cc4[jj] >= 1) && (cc4[jj] <= 64);
                sIdx[n][jj][px] = (u16)(inb ? ((rr4[jj] - 1) * 64 + (cc4[jj] - 1)) : 0);
                sWgt[n][jj][px] = inb ? gg4[jj] : 0.f;
            }
        }
    }
    __syncthreads();

    int lane  = t & 63;
    int wv    = t >> 6;          // wave 0..7
    int col   = lane & 15, quad = lane >> 4;
    int ow    = wv & 3;          // o 64-range
    int ph    = wv >> 2;         // px half (0/1)
    int sp_px = t >> 3;          // sampling pixel 0..63
    int sp_oc = t & 7;           // sampling channel octet

    const f16* txb = tx + (size_t)b * HWn * INCc;
    const f16* whb = wh + (size_t)b * (NC * 16384);

    auto sample = [&](int KC) {
        int n_ = KC >> 1;
        int co = ((KC & 1) << 6) + sp_oc * 8;
        const f16* p0 = txb + (size_t)sIdx[n_][0][sp_px] * INCc + co;
        const f16* p1 = txb + (size_t)sIdx[n_][1][sp_px] * INCc + co;
        const f16* p2 = txb + (size_t)sIdx[n_][2][sp_px] * INCc + co;
        const f16* p3 = txb + (size_t)sIdx[n_][3][sp_px] * INCc + co;
        float g0 = sWgt[n_][0][sp_px], g1 = sWgt[n_][1][sp_px];
        float g2 = sWgt[n_][2][sp_px], g3 = sWgt[n_][3][sp_px];
        h8 v0 = *(const h8*)p0;
        h8 v1 = *(const h8*)p1;
        h8 v2 = *(const h8*)p2;
        h8 v3 = *(const h8*)p3;
        h8 res;
#pragma unroll
        for (int i = 0; i < 8; i++)
            res[i] = (f16)(g0 * (float)v0[i] + g1 * (float)v1[i]
                         + g2 * (float)v2[i] + g3 * (float)v3[i]);
        *(h8*)&Xs[sp_px][(sp_oc ^ (sp_px & 7)) * 8] = res;
    };

    auto dmaW = [&](int KC) {
        const f16* src = whb + (size_t)KC * 16384;
#pragma unroll
        for (int i = 0; i < 4; i++) {
            int seg = i * 8 + wv;                        // uniform per wave
            const f16* g = src + seg * 512 + lane * 8;   // 16 B per lane
            f16* l = &Wb[seg * 512];
            __builtin_amdgcn_global_load_lds(
                (const __attribute__((address_space(1))) u32*)g,
                (__attribute__((address_space(3))) u32*)l, 16, 0, 0);
        }
    };

    f4 acc[4][2];
#pragma unroll
    for (int oi = 0; oi < 4; oi++)
#pragma unroll
        for (int pj = 0; pj < 2; pj++) acc[oi][pj] = (f4){0.f, 0.f, 0.f, 0.f};

    dmaW(0);
    sample(0);
    __syncthreads();

    for (int kc = 0; kc < NC; kc++) {
        h8 Af[4][2], Bf[2][2];
#pragma unroll
        for (int oi = 0; oi < 4; oi++)
#pragma unroll
            for (int ks = 0; ks < 2; ks++) {
                int rr   = ow * 64 + oi * 16 + col;
                int slot = (ks * 4 + quad) ^ (col & 7);
                Af[oi][ks] = *(const h8*)&Wb[rr * 64 + slot * 8];
            }
#pragma unroll
        for (int pj = 0; pj < 2; pj++)
#pragma unroll
            for (int ks = 0; ks < 2; ks++) {
                int px   = ph * 32 + pj * 16 + col;
                int slot = (ks * 4 + quad) ^ (px & 7);
                Bf[pj][ks] = *(const h8*)&Xs[px][slot * 8];
            }
        __syncthreads();                      // frag reads done -> overwrite ok
        if (kc < NC - 1) { dmaW(kc + 1); sample(kc + 1); }
#pragma unroll
        for (int oi = 0; oi < 4; oi++)
#pragma unroll
            for (int pj = 0; pj < 2; pj++) {
                acc[oi][pj] = __builtin_amdgcn_mfma_f32_16x16x32_f16(Af[oi][0], Bf[pj][0], acc[oi][pj], 0, 0, 0);
                acc[oi][pj] = __builtin_amdgcn_mfma_f32_16x16x32_f16(Af[oi][1], Bf[pj][1], acc[oi][pj], 0, 0, 0);
            }
        __syncthreads();                      // DMA + sample landed
    }

    // ---- epilogue: frag reg r = gate r for ch = ow*16 + oi*4 + quad ----
#pragma unroll
    for (int oi = 0; oi < 4; oi++) {
        int ch = ow * 16 + oi * 4 + quad;
#pragma unroll
        for (int pj = 0; pj < 2; pj++) {
            int wpos = ph * 32 + pj * 16 + col;
            f4 a = acc[oi][pj];
            float ci  = a[0] + bmS[ch];
            float cf  = a[1] + bmS[64 + ch];
            float co  = a[2] + bmS[128 + ch];
            float cgv = a[3] + bmS[192 + ch];
            float ig  = sigf(ci);
            float fg  = sigf(cf);
            float og_ = sigf(co);
            float gg  = tanhfast(cgv);
            size_t idx = (((size_t)(b * HIDc + ch)) * 64 + h) * 64 + wpos;
            float cp = ccur[idx];
            float cn = fg * cp + ig * gg;
            out[idx] = og_ * tanhfast(cn);                   // h_next
            out[(size_t)Bn * HIDc * HWn + idx] = cn;         // c_next
        }
    }
}

// ---------------------------------------------------------------------------
extern "C" void kernel_launch(void* const* d_in, const int* in_sizes, int n_in,
                              void* d_out, int out_size, void* d_ws, size_t ws_size,
                              hipStream_t stream)
{
    const float* xin  = (const float*)d_in[0];
    const float* hcur = (const float*)d_in[1];
    const float* ccur = (const float*)d_in[2];
    const float* meta = (const float*)d_in[3];
    const float* moff = (const float*)d_in[4];
    const float* w1w  = (const float*)d_in[5];
    const float* w1b  = (const float*)d_in[6];
    const float* w2w  = (const float*)d_in[7];
    const float* w2b  = (const float*)d_in[8];
    const float* blw  = (const float*)d_in[9];
    const float* blb  = (const float*)d_in[10];
    const float* pw   = (const float*)d_in[11];
    const float* pb   = (const float*)d_in[12];
    float* out = (float*)d_out;
    float* bm  = (float*)d_ws;
    f16* f16b  = (f16*)((char*)d_ws + F16_BYTE);
    f16* tx  = f16b + TX_F;
    f16* wh  = f16b + WH_F;
    f16* m1h = f16b + M1H_F;
    f16* m1l = f16b + M1L_F;

    hipLaunchKernelGGL(k_tr,    dim3(256), dim3(256), 0, stream, xin, hcur, tx);
    hipLaunchKernelGGL(k_hyper, dim3(516), dim3(256), 0, stream,
                       meta, w1w, w1b, blw, blb, bm, m1h, m1l);
    hipLaunchKernelGGL(k_w2,    dim3(576), dim3(256), 0, stream,
                       w2w, w2b, m1h, m1l, wh);
    hipLaunchKernelGGL(k_main,  dim3(256), dim3(512), 0, stream,
                       tx, ccur, moff, pw, pb, bm, wh, out);
}

// Round 8
// 146.605 us; speedup vs baseline: 1.9838x; 1.0374x over previous
//
#include <hip/hip_runtime.h>
#include <math.h>

#define Bn    4
#define HIDc  64          // hidden / input channels each = 64
#define INCc  128         // concat channels
#define OUTCc 256         // 4*HID gates
#define Dd    256         // meta dim
#define NT    9           // K*K taps
#define HWn   4096        // 64*64
#define NC    18          // K=1152 in 64-chunks, k = n*128 + c

typedef _Float16 f16;
typedef unsigned short u16;
typedef unsigned int u32;
typedef __attribute__((ext_vector_type(8))) _Float16 h8;   // 8 fp16 (4 VGPRs)
typedef __attribute__((ext_vector_type(4))) _Float16 h4;   // 4 fp16 (8B)
typedef __attribute__((ext_vector_type(4))) float f4;      // MFMA C/D frag

// ---- workspace layout ----
// floats: bm [B][OUTC] = 1024 floats at offset 0
// f16 region (elem offsets from byte 4096):
//   TX  [B][4096 pos][128 ch]                     2,097,152
//   WH  [B][18 kc][256 rr][8 slot][8 e]           1,179,648  (granule-swizzled)
//   M1H [B][128 c][256 d], M1L same                 131,072 each
#define F16_BYTE 4096
#define TX_F   ((size_t)0)
#define WH_F   ((size_t)2097152)
#define M1H_F  ((size_t)3276800)
#define M1L_F  ((size_t)3407872)

__device__ __forceinline__ float sigf(float x) { return 1.f / (1.f + __expf(-x)); }
__device__ __forceinline__ float tanhfast(float x) {
    float a = fabsf(x);
    float e = __expf(2.f * a);
    float t = 1.f - 2.f / (e + 1.f);
    return copysignf(t, x);
}

// ---------------------------------------------------------------------------
// Kernel 0 (fused): blocks 0..255  = k_tr   (channel-last fp16 copy of x||h)
//                   blocks 256..771 = k_hyper (wm1 rows -> fp16 hi/lo, bl -> bm)
// ---------------------------------------------------------------------------
__global__ void __launch_bounds__(256)
k_prep(const float* __restrict__ xin, const float* __restrict__ hcur,
       f16* __restrict__ tx, const float* __restrict__ meta,
       const float* __restrict__ w1w, const float* __restrict__ w1b,
       const float* __restrict__ blw, const float* __restrict__ blb,
       float* __restrict__ bm, f16* __restrict__ m1h, f16* __restrict__ m1l)
{
    __shared__ __align__(16) float sm[Bn * Dd];
    int t = threadIdx.x;
    int bid = blockIdx.x;

    if (bid < 256) {                          // ---- k_tr path ----
        int b = bid >> 6, h = bid & 63;
        int w = t & 63, oq = t >> 6;          // oq 0..3
        const float* xb = xin  + ((size_t)b * HIDc) * HWn + h * 64;
        const float* hb = hcur + ((size_t)b * HIDc) * HWn + h * 64;
        f16* dst = tx + ((size_t)(b * HWn + h * 64 + w)) * INCc;
#pragma unroll
        for (int s = 0; s < 4; s++) {
            int c0 = (oq + s * 4) * 8;        // 0..120
            h8 v;
#pragma unroll
            for (int i = 0; i < 8; i++) {
                int ci = c0 + i;
                float f = (ci < HIDc) ? xb[(size_t)ci * HWn + w]
                                      : hb[(size_t)(ci - HIDc) * HWn + w];
                v[i] = (f16)f;
            }
            *(h8*)(dst + c0) = v;
        }
        return;
    }

    // ---- k_hyper path ----
    int hbid = bid - 256;                     // 0..515
    for (int i = t; i < Bn * Dd; i += 256) sm[i] = meta[i];
    __syncthreads();

    int lane = t & 63, wvv = t >> 6;
    int rl = lane >> 4, dl = lane & 15;
    int rbase = hbid * 64 + wvv * 16;

#pragma unroll
    for (int g = 0; g < 4; g++) {
        int r = rbase + g * 4 + rl;
        bool isbl = (r >= INCc * Dd);
        const float* row = isbl ? (blw + (size_t)(r - INCc * Dd) * Dd)
                                : (w1w + (size_t)r * Dd);
        float a0 = 0.f, a1 = 0.f, a2 = 0.f, a3 = 0.f;
#pragma unroll
        for (int it = 0; it < 4; it++) {
            int d = it * 64 + dl * 4;
            float4 wv = *(const float4*)(row + d);
            float4 m0 = *(const float4*)&sm[0 * Dd + d];
            float4 m1 = *(const float4*)&sm[1 * Dd + d];
            float4 m2 = *(const float4*)&sm[2 * Dd + d];
            float4 m3 = *(const float4*)&sm[3 * Dd + d];
            a0 += wv.x*m0.x + wv.y*m0.y + wv.z*m0.z + wv.w*m0.w;
            a1 += wv.x*m1.x + wv.y*m1.y + wv.z*m1.z + wv.w*m1.w;
            a2 += wv.x*m2.x + wv.y*m2.y + wv.z*m2.z + wv.w*m2.w;
            a3 += wv.x*m3.x + wv.y*m3.y + wv.z*m3.z + wv.w*m3.w;
        }
#pragma unroll
        for (int mk = 1; mk <= 8; mk <<= 1) {
            a0 += __shfl_xor(a0, mk); a1 += __shfl_xor(a1, mk);
            a2 += __shfl_xor(a2, mk); a3 += __shfl_xor(a3, mk);
        }
        if (dl == 0) {
            if (isbl) {
                int rb = r - INCc * Dd;
                float bb = blb[rb];
                bm[0*OUTCc + rb] = a0 + bb;
                bm[1*OUTCc + rb] = a1 + bb;
                bm[2*OUTCc + rb] = a2 + bb;
                bm[3*OUTCc + rb] = a3 + bb;
            } else {
                float bb = w1b[r];
                float v[4] = {a0 + bb, a1 + bb, a2 + bb, a3 + bb};
#pragma unroll
                for (int bi = 0; bi < 4; bi++) {
                    f16 hi = (f16)v[bi];
                    f16 lo = (f16)(v[bi] - (float)hi);
                    m1h[(size_t)bi * 32768 + r] = hi;
                    m1l[(size_t)bi * 32768 + r] = lo;
                }
            }
        }
    }
}

// ---------------------------------------------------------------------------
// Kernel 2: per-sample hyper GEMM via fp16 MFMA, A = wm1 (hi/lo split),
// B = w2_w (fp16 RN, converted during staging). K=256 fully LDS-resident,
// ONE barrier. Tile 32c x 64j, 576 blocks. Stride-256 rows + granule-XOR
// swizzle (g -> g^(row&7)), 64 KB LDS. Epilogue: 4 consecutive kk per (cf)
// share one WH granule -> packed 8B stores.
// ---------------------------------------------------------------------------
__global__ void __launch_bounds__(256)
k_w2(const float* __restrict__ w2w, const float* __restrict__ w2b,
     const f16* __restrict__ m1h, const f16* __restrict__ m1l,
     f16* __restrict__ wh)
{
    int bid = blockIdx.x;
    int b   = bid / 144;
    int rem = bid % 144;
    int c0  = (rem / 36) * 32;
    int j0  = (rem % 36) * 64;

    __shared__ __align__(16) f16 Ah[32][256];   // granule-XOR swizzled
    __shared__ __align__(16) f16 Al[32][256];
    __shared__ __align__(16) f16 Bh[64][256];

    int t = threadIdx.x;
    {   // stage A (hi/lo): row 0..31, seg 0..7 -> granules seg*4+i (i<4)
        int row = t >> 3, seg = t & 7;
        const f16* sh = m1h + (size_t)b * 32768 + (size_t)(c0 + row) * 256 + seg * 32;
        const f16* sl = m1l + (size_t)b * 32768 + (size_t)(c0 + row) * 256 + seg * 32;
#pragma unroll
        for (int i = 0; i < 4; i++) {
            int gsl = ((seg * 4 + i) ^ (row & 7)) * 8;
            *(h8*)&Ah[row][gsl] = *(const h8*)(sh + i * 8);
            *(h8*)&Al[row][gsl] = *(const h8*)(sl + i * 8);
        }
        // stage B (fp32 -> fp16 convert): row2 0..63, seg2 0..3 -> granules seg2*8+i
        int row2 = t >> 2, seg2 = t & 3;
        const float* sb = w2w + (size_t)(j0 + row2) * 256 + seg2 * 64;
#pragma unroll
        for (int i = 0; i < 8; i++) {
            float4 x0 = *(const float4*)(sb + i * 8);
            float4 x1 = *(const float4*)(sb + i * 8 + 4);
            h8 v = {(f16)x0.x, (f16)x0.y, (f16)x0.z, (f16)x0.w,
                    (f16)x1.x, (f16)x1.y, (f16)x1.z, (f16)x1.w};
            *(h8*)&Bh[row2][((seg2 * 8 + i) ^ (row2 & 7)) * 8] = v;
        }
    }
    __syncthreads();

    int lane = t & 63, jw = t >> 6;
    int col = lane & 15, quad = lane >> 4;

    f4 acc[2];
    acc[0] = (f4){0.f, 0.f, 0.f, 0.f};
    acc[1] = (f4){0.f, 0.f, 0.f, 0.f};
#pragma unroll
    for (int ks = 0; ks < 8; ks++) {
        int gsl = ((ks * 4 + quad) ^ (col & 7)) * 8;
        h8 Bf = *(const h8*)&Bh[jw * 16 + col][gsl];
#pragma unroll
        for (int cf = 0; cf < 2; cf++) {
            h8 Ahf = *(const h8*)&Ah[cf * 16 + col][gsl];
            h8 Alf = *(const h8*)&Al[cf * 16 + col][gsl];
            acc[cf] = __builtin_amdgcn_mfma_f32_16x16x32_f16(Ahf, Bf, acc[cf], 0, 0, 0);
            acc[cf] = __builtin_amdgcn_mfma_f32_16x16x32_f16(Alf, Bf, acc[cf], 0, 0, 0);
        }
    }

    int j = j0 + jw * 16 + col;
    int o = j / 9, n = j - o * 9;
    float bias = w2b[j];
    int rr = ((o & 63) << 2) | (o >> 6);
    f16* whb = wh + (size_t)b * (NC * 16384);
#pragma unroll
    for (int cf = 0; cf < 2; cf++) {
        int cbase = c0 + cf * 16 + quad * 4;      // multiple of 4
        int k0  = n * 128 + cbase;
        int kc  = k0 >> 6, kk0 = k0 & 63;         // kk0 % 4 == 0
        int slot = (kk0 >> 3) ^ (rr & 7);
        h4 pk;
#pragma unroll
        for (int rg = 0; rg < 4; rg++) pk[rg] = (f16)(acc[cf][rg] + bias);
        *(h4*)&whb[((size_t)kc * 256 + rr) * 64 + slot * 8 + (kk0 & 7)] = pk;
    }
}

// ---------------------------------------------------------------------------
// Kernel 3: REVERTED to the R6-proven two-barrier single-buffer structure.
// 512 thr / 8 waves, 64 px (full h-row) x 256 o per block, 256 blocks
// (1/CU). W chunk (32 KB) staged via async global_load_lds into a SINGLE
// LDS buffer; X sampled into single 8 KB buffer; per chunk: frag ds_reads
// -> regs, barrier, overwrite (DMA + sample kc+1), MFMA, barrier.
// (R7's single-barrier double-buffer variant raced on warm replays —
//  cold-pass/warm-fail, tripwire-consistent wrong output. Do not re-land
//  without an asm-level audit of the barrier waitcnt placement.)
// ---------------------------------------------------------------------------
__global__ void __launch_bounds__(512)
k_main(const f16* __restrict__ tx, const float* __restrict__ ccur,
       const float* __restrict__ moff, const float* __restrict__ pw,
       const float* __restrict__ pb, const float* __restrict__ bm,
       const f16* __restrict__ wh, float* __restrict__ out)
{
    int bid = blockIdx.x;
    int xcd = bid & 7;
    int b   = xcd >> 1;                       // 2 XCD slots per sample
    int h   = ((bid >> 3) << 1) | (xcd & 1);  // 0..63

    __shared__ u16   sIdx[NT][4][64];
    __shared__ float sWgt[NT][4][64];
    __shared__ __align__(16) f16 Wb[256 * 64];   // 32 KB, granule-swizzled
    __shared__ __align__(16) f16 Xs[64][64];     // 8 KB, granule-swizzled
    __shared__ float bmS[OUTCc];

    int t = threadIdx.x;
    if (t < 256) bmS[t] = bm[b * OUTCc + t];

    // ---- phase 0: offset conv + bilinear tables for 64 px x 9 taps ----
    {
        int px = t & 63;
        int nh = t >> 6;                      // 0..7
        for (int n = nh; n < NT; n += 8) {
            float ox = pb[n], oy = pb[NT + n];
#pragma unroll
            for (int ii = 0; ii < 3; ii++) {
#pragma unroll
                for (int jj = 0; jj < 3; jj++) {
                    int rr = h - 1 + ii, cc = px - 1 + jj;
                    float m = (rr >= 0 && rr < 64 && cc >= 0 && cc < 64)
                              ? moff[(size_t)b * HWn + rr * 64 + cc] : 0.f;
                    ox = fmaf(pw[(size_t)n * 9 + ii * 3 + jj], m, ox);
                    oy = fmaf(pw[(size_t)(NT + n) * 9 + ii * 3 + jj], m, oy);
                }
            }
            float pr = (float)(h + (n / 3)) + ox;
            float pc = (float)(px + (n % 3)) + oy;
            float fr = floorf(pr), fc = floorf(pc);
            float ltr = fminf(fmaxf(fr, 0.f), 65.f);
            float ltc = fminf(fmaxf(fc, 0.f), 65.f);
            float rbr = fminf(fmaxf(fr + 1.f, 0.f), 65.f);
            float rbc = fminf(fmaxf(fc + 1.f, 0.f), 65.f);
            float cpr = fminf(fmaxf(pr, 0.f), 65.f);
            float cpc = fminf(fmaxf(pc, 0.f), 65.f);
            float ar = 1.f + ltr - cpr, br = 1.f - rbr + cpr;
            float ac = 1.f + ltc - cpc, bc = 1.f - rbc + cpc;
            int ir0 = (int)ltr, ic0 = (int)ltc, ir1 = (int)rbr, ic1 = (int)rbc;
            int   rr4[4] = {ir0, ir1, ir0, ir1};
            int   cc4[4] = {ic0, ic1, ic1, ic0};
            float gg4[4] = {ar * ac, br * bc, ar * bc, br * ac};
#pragma unroll
            for (int jj = 0; jj < 4; jj++) {
                bool inb = (rr4[jj] >= 1) && (rr4[jj] <= 64) &&
                           (cc4[jj] >= 1) && (cc4[jj] <= 64);
                sIdx[n][jj][px] = (u16)(inb ? ((rr4[jj] - 1) * 64 + (cc4[jj] - 1)) : 0);
                sWgt[n][jj][px] = inb ? gg4[jj] : 0.f;
            }
        }
    }
    __syncthreads();

    int lane  = t & 63;
    int wv    = t >> 6;          // wave 0..7
    int col   = lane & 15, quad = lane >> 4;
    int ow    = wv & 3;          // o 64-range
    int ph    = wv >> 2;         // px half (0/1)
    int sp_px = t >> 3;          // sampling pixel 0..63
    int sp_oc = t & 7;           // sampling channel octet

    const f16* txb = tx + (size_t)b * HWn * INCc;
    const f16* whb = wh + (size_t)b * (NC * 16384);

    auto sample = [&](int KC) {
        int n_ = KC >> 1;
        int co = ((KC & 1) << 6) + sp_oc * 8;
        const f16* p0 = txb + (size_t)sIdx[n_][0][sp_px] * INCc + co;
        const f16* p1 = txb + (size_t)sIdx[n_][1][sp_px] * INCc + co;
        const f16* p2 = txb + (size_t)sIdx[n_][2][sp_px] * INCc + co;
        const f16* p3 = txb + (size_t)sIdx[n_][3][sp_px] * INCc + co;
        float g0 = sWgt[n_][0][sp_px], g1 = sWgt[n_][1][sp_px];
        float g2 = sWgt[n_][2][sp_px], g3 = sWgt[n_][3][sp_px];
        h8 v0 = *(const h8*)p0;
        h8 v1 = *(const h8*)p1;
        h8 v2 = *(const h8*)p2;
        h8 v3 = *(const h8*)p3;
        h8 res;
#pragma unroll
        for (int i = 0; i < 8; i++)
            res[i] = (f16)(g0 * (float)v0[i] + g1 * (float)v1[i]
                         + g2 * (float)v2[i] + g3 * (float)v3[i]);
        *(h8*)&Xs[sp_px][(sp_oc ^ (sp_px & 7)) * 8] = res;
    };

    auto dmaW = [&](int KC) {
        const f16* src = whb + (size_t)KC * 16384;
#pragma unroll
        for (int i = 0; i < 4; i++) {
            int seg = i * 8 + wv;                        // uniform per wave
            const f16* g = src + seg * 512 + lane * 8;   // 16 B per lane
            f16* l = &Wb[seg * 512];
            __builtin_amdgcn_global_load_lds(
                (const __attribute__((address_space(1))) u32*)g,
                (__attribute__((address_space(3))) u32*)l, 16, 0, 0);
        }
    };

    f4 acc[4][2];
#pragma unroll
    for (int oi = 0; oi < 4; oi++)
#pragma unroll
        for (int pj = 0; pj < 2; pj++) acc[oi][pj] = (f4){0.f, 0.f, 0.f, 0.f};

    dmaW(0);
    sample(0);
    __syncthreads();

    for (int kc = 0; kc < NC; kc++) {
        h8 Af[4][2], Bf[2][2];
#pragma unroll
        for (int oi = 0; oi < 4; oi++)
#pragma unroll
            for (int ks = 0; ks < 2; ks++) {
                int rr   = ow * 64 + oi * 16 + col;
                int slot = (ks * 4 + quad) ^ (col & 7);
                Af[oi][ks] = *(const h8*)&Wb[rr * 64 + slot * 8];
            }
#pragma unroll
        for (int pj = 0; pj < 2; pj++)
#pragma unroll
            for (int ks = 0; ks < 2; ks++) {
                int px   = ph * 32 + pj * 16 + col;
                int slot = (ks * 4 + quad) ^ (px & 7);
                Bf[pj][ks] = *(const h8*)&Xs[px][slot * 8];
            }
        __syncthreads();                      // frag reads done -> overwrite ok
        if (kc < NC - 1) { dmaW(kc + 1); sample(kc + 1); }
#pragma unroll
        for (int oi = 0; oi < 4; oi++)
#pragma unroll
            for (int pj = 0; pj < 2; pj++) {
                acc[oi][pj] = __builtin_amdgcn_mfma_f32_16x16x32_f16(Af[oi][0], Bf[pj][0], acc[oi][pj], 0, 0, 0);
                acc[oi][pj] = __builtin_amdgcn_mfma_f32_16x16x32_f16(Af[oi][1], Bf[pj][1], acc[oi][pj], 0, 0, 0);
            }
        __syncthreads();                      // DMA + sample landed
    }

    // ---- epilogue: frag reg r = gate r for ch = ow*16 + oi*4 + quad ----
#pragma unroll
    for (int oi = 0; oi < 4; oi++) {
        int ch = ow * 16 + oi * 4 + quad;
#pragma unroll
        for (int pj = 0; pj < 2; pj++) {
            int wpos = ph * 32 + pj * 16 + col;
            f4 a = acc[oi][pj];
            float ci  = a[0] + bmS[ch];
            float cf  = a[1] + bmS[64 + ch];
            float co  = a[2] + bmS[128 + ch];
            float cgv = a[3] + bmS[192 + ch];
            float ig  = sigf(ci);
            float fg  = sigf(cf);
            float og_ = sigf(co);
            float gg  = tanhfast(cgv);
            size_t idx = (((size_t)(b * HIDc + ch)) * 64 + h) * 64 + wpos;
            float cp = ccur[idx];
            float cn = fg * cp + ig * gg;
            out[idx] = og_ * tanhfast(cn);                   // h_next
            out[(size_t)Bn * HIDc * HWn + idx] = cn;         // c_next
        }
    }
}

// ---------------------------------------------------------------------------
extern "C" void kernel_launch(void* const* d_in, const int* in_sizes, int n_in,
                              void* d_out, int out_size, void* d_ws, size_t ws_size,
                              hipStream_t stream)
{
    const float* xin  = (const float*)d_in[0];
    const float* hcur = (const float*)d_in[1];
    const float* ccur = (const float*)d_in[2];
    const float* meta = (const float*)d_in[3];
    const float* moff = (const float*)d_in[4];
    const float* w1w  = (const float*)d_in[5];
    const float* w1b  = (const float*)d_in[6];
    const float* w2w  = (const float*)d_in[7];
    const float* w2b  = (const float*)d_in[8];
    const float* blw  = (const float*)d_in[9];
    const float* blb  = (const float*)d_in[10];
    const float* pw   = (const float*)d_in[11];
    const float* pb   = (const float*)d_in[12];
    float* out = (float*)d_out;
    float* bm  = (float*)d_ws;
    f16* f16b  = (f16*)((char*)d_ws + F16_BYTE);
    f16* tx  = f16b + TX_F;
    f16* wh  = f16b + WH_F;
    f16* m1h = f16b + M1H_F;
    f16* m1l = f16b + M1L_F;

    hipLaunchKernelGGL(k_prep, dim3(772), dim3(256), 0, stream,
                       xin, hcur, tx, meta, w1w, w1b, blw, blb, bm, m1h, m1l);
    hipLaunchKernelGGL(k_w2,   dim3(576), dim3(256), 0, stream,
                       w2w, w2b, m1h, m1l, wh);
    hipLaunchKernelGGL(k_main, dim3(256), dim3(512), 0, stream,
                       tx, ccur, moff, pw, pb, bm, wh, out);
}